// Round 5
// baseline (770.084 us; speedup 1.0000x reference)
//
#include <hip/hip_runtime.h>

#define B_ 8
#define S_ 4096
#define IN_ 64
#define HID_ 512
#define NSTEP 12
#define SP_ (S_ + 2)
#define NP_ (B_ * SP_)
#define NTOT (B_ * S_)

typedef unsigned short u16;
typedef __attribute__((ext_vector_type(8))) short bf16x8;
typedef __attribute__((ext_vector_type(4))) float f32x4;
typedef __attribute__((ext_vector_type(16))) float f32x16;

__device__ __forceinline__ u16 f2bf(float f) {
  unsigned u = __float_as_uint(f);
  u += 0x7fffu + ((u >> 16) & 1u);
  return (u16)(u >> 16);
}

__device__ __forceinline__ void gload16(const void* g, void* l) {
  __builtin_amdgcn_global_load_lds((const __attribute__((address_space(1))) void*)g,
                                   (__attribute__((address_space(3))) void*)l, 16, 0, 0);
}

// ---------------- setup: bf16 conversions + weight transposes + pad-row zeroing ----------------
__global__ void setup_kernel(const float* __restrict__ x, const float* __restrict__ Wc,
                             const float* __restrict__ Wi, const float* __restrict__ Wo,
                             u16* __restrict__ wcb, u16* __restrict__ wib,
                             u16* __restrict__ wob, u16* __restrict__ xbf,
                             u16* __restrict__ h0, u16* __restrict__ h1) {
  const int n_wc = 3 * HID_ * HID_;       // wcb[k][o][i] = Wc[o][i][k]
  const int n_wio = IN_ * HID_;
  const int n_xb = NTOT * IN_;
  const int n_pad = 2 * B_ * 2 * HID_;
  const long total = (long)n_wc + 2 * n_wio + n_xb + n_pad;
  for (long u = (long)blockIdx.x * blockDim.x + threadIdx.x; u < total;
       u += (long)gridDim.x * blockDim.x) {
    long v = u;
    if (v < n_wc) {
      int k = (int)(v / (HID_ * HID_));
      int rem = (int)(v % (HID_ * HID_));
      int o = rem / HID_, i = rem % HID_;
      wcb[v] = f2bf(Wc[((long)o * HID_ + i) * 3 + k]);
    } else if ((v -= n_wc) < n_wio) {      // wib[i][j] = Wi[j][i]
      int i = (int)(v / IN_), j = (int)(v % IN_);
      wib[v] = f2bf(Wi[j * HID_ + i]);
    } else if ((v -= n_wio) < n_wio) {     // wob[j][i] = Wo[i][j]
      int j = (int)(v / HID_), i = (int)(v % HID_);
      wob[v] = f2bf(Wo[i * IN_ + j]);
    } else if ((v -= n_wio) < n_xb) {
      xbf[v] = f2bf(x[v]);
    } else {
      v -= n_xb;                           // zero pad rows (s=-1 and s=S per batch, both buffers)
      int buf = (int)(v / (B_ * 2 * HID_));
      int r = (int)(v % (B_ * 2 * HID_));
      int b = r / (2 * HID_);
      int q = r % (2 * HID_);
      int side = q / HID_, i = q % HID_;
      long p = (long)b * SP_ + (side ? (S_ + 1) : 0);
      (buf ? h1 : h0)[p * HID_ + i] = 0;
    }
  }
}

// ---------------- proj_in: h0[n][i] = x[n][:] @ W_in[:,i] + b_in  (bf16 MFMA, K=64) ----------------
__global__ __launch_bounds__(256, 2) void proj_in_gemm(const u16* __restrict__ xb,
                                                       const u16* __restrict__ wib,
                                                       const float* __restrict__ bin,
                                                       u16* __restrict__ hout) {
  __shared__ __align__(16) u16 Ab[128 * 64];
  __shared__ __align__(16) u16 Bb[128 * 64];
  const int tid = threadIdx.x, wid = tid >> 6, lane = tid & 63;
  const int nt = blockIdx.x, mt = blockIdx.y;
  const int wr = wid >> 1, wcn = wid & 1, fr = lane & 15, fq = lane >> 4;
#pragma unroll
  for (int c = 0; c < 4; ++c) {
    const int ch = wid * 4 + c;
    const int row = ch * 8 + (lane >> 3), cb = (lane & 7) * 8;
    gload16(wib + (mt * 128 + row) * 64 + cb, &Ab[ch * 512]);
    gload16(xb + ((long)nt * 128 + row) * 64 + cb, &Bb[ch * 512]);
  }
  f32x4 acc[4][4];
#pragma unroll
  for (int m = 0; m < 4; ++m)
#pragma unroll
    for (int n = 0; n < 4; ++n) acc[m][n] = {0.f, 0.f, 0.f, 0.f};
  __syncthreads();
#pragma unroll
  for (int t = 0; t < 2; ++t) {
    const int j0 = t * 32;
    bf16x8 af[4], bfv[4];
#pragma unroll
    for (int m = 0; m < 4; ++m)
      af[m] = *(const bf16x8*)&Ab[(wr * 64 + m * 16 + fr) * 64 + j0 + fq * 8];
#pragma unroll
    for (int n = 0; n < 4; ++n)
      bfv[n] = *(const bf16x8*)&Bb[(wcn * 64 + n * 16 + fr) * 64 + j0 + fq * 8];
#pragma unroll
    for (int m = 0; m < 4; ++m)
#pragma unroll
      for (int n = 0; n < 4; ++n)
        acc[m][n] = __builtin_amdgcn_mfma_f32_16x16x32_bf16(af[m], bfv[n], acc[m][n], 0, 0, 0);
  }
  const int n0 = nt * 128;
  const int bb = n0 / S_, s0v = n0 % S_;
  const int prow = bb * SP_ + s0v + 1;
#pragma unroll
  for (int m = 0; m < 4; ++m) {
    const int i = mt * 128 + wr * 64 + m * 16 + fq * 4;
    const float4 bias = *(const float4*)&bin[i];
#pragma unroll
    for (int n = 0; n < 4; ++n) {
      const int nl = wcn * 64 + n * 16 + fr;
      const long p = prow + nl;
      union { u16 q[4]; uint2 v; } u;
      u.q[0] = f2bf(acc[m][n][0] + bias.x);
      u.q[1] = f2bf(acc[m][n][1] + bias.y);
      u.q[2] = f2bf(acc[m][n][2] + bias.z);
      u.q[3] = f2bf(acc[m][n][3] + bias.w);
      *(uint2*)&hout[p * HID_ + i] = u.v;
    }
  }
}

// ---------------- conv step: 256x256 tile, 4 waves x (128x128), 32x32x16 MFMA ----------------
// C[o,n] = relu(sum_{k,i} W[o,i,k] h[i,n+k-1] + b), bf16 in/out.
// K-units u = 0..47: tap kk=u%3, i-slice i0=(u/3)*32 (tap-inner: B re-reads L2-hot).
// LDS: 4 bufs x 32KB (A [256][32] + B [256][32] bf16, 64-B rows), depth-3 prefetch.
// Swizzle: byte ^= ((row>>1)&3)<<4 -> 8 consecutive lanes hit 8 distinct 16B slots.
// Body t: vmcnt(8)+barrier gate -> issue tile-t+1 ds_reads (other frag set) ->
// stage(t+3) -> 32 MFMA on tile-t frags. Reg-dbuf'd frags let tile-t+1's LDS
// service overlap tile-t's MFMA (compiler auto-lgkmcnt on SSA deps).
#define ISSUE_READS(T, AF, BF) {                                             \
  const char* _b = (const char*)smem + ((T) & 3) * 32768;                    \
  _Pragma("unroll")                                                          \
  for (int mf = 0; mf < 4; ++mf) {                                           \
    AF[0][mf] = *(const bf16x8*)(_b + aoff0 + mf * 2048);                    \
    AF[1][mf] = *(const bf16x8*)(_b + aoff1 + mf * 2048);                    \
  }                                                                          \
  _Pragma("unroll")                                                          \
  for (int nf = 0; nf < 4; ++nf) {                                           \
    BF[0][nf] = *(const bf16x8*)(_b + 16384 + boff0 + nf * 2048);            \
    BF[1][nf] = *(const bf16x8*)(_b + 16384 + boff1 + nf * 2048);            \
  } }

#define DO_MFMA(AF, BF)                                                      \
  _Pragma("unroll")                                                          \
  for (int kh = 0; kh < 2; ++kh)                                             \
    _Pragma("unroll")                                                        \
    for (int mf = 0; mf < 4; ++mf)                                           \
      _Pragma("unroll")                                                      \
      for (int nf = 0; nf < 4; ++nf)                                         \
        acc[mf][nf] = __builtin_amdgcn_mfma_f32_32x32x16_bf16(AF[kh][mf], BF[kh][nf], acc[mf][nf], 0, 0, 0);

#define BODY(T, AFc, BFc, AFn, BFn) {                                        \
  asm volatile("s_waitcnt vmcnt(8)" ::: "memory");                           \
  __builtin_amdgcn_sched_barrier(0);                                         \
  __builtin_amdgcn_s_barrier();                                              \
  __builtin_amdgcn_sched_barrier(0);                                         \
  if ((T) < 47) { ISSUE_READS((T) + 1, AFn, BFn); }                          \
  __builtin_amdgcn_sched_barrier(0);                                         \
  stage((T) + 3);                                                            \
  __builtin_amdgcn_sched_barrier(0);                                         \
  __builtin_amdgcn_s_setprio(1);                                             \
  DO_MFMA(AFc, BFc);                                                         \
  __builtin_amdgcn_s_setprio(0);                                             \
  __builtin_amdgcn_sched_barrier(0); }

__global__ __launch_bounds__(256, 1) void conv_gemm5(const u16* __restrict__ hin,
                                                     u16* __restrict__ hout,
                                                     const u16* __restrict__ wcb,
                                                     const float* __restrict__ bconv) {
  extern __shared__ __align__(16) u16 smem[];
  const int tid = threadIdx.x;
  const int w = tid >> 6, lane = tid & 63;
  const int wm = w >> 1, wn = w & 1;          // 2 x 2 wave grid; per-wave C = 128 x 128
  const int r32 = lane & 31, khi = lane >> 5;
  const int mbase = blockIdx.y * 256;
  const int n0 = blockIdx.x * 256;
  const int bb = n0 / S_, s0 = n0 % S_;
  const int prow0 = bb * SP_ + s0;            // tap-k B rows start at prow0+k

  // staging coords per round q: linear byte d = tid*16 + q*4096 within a 16KB region;
  // logical row = d>>6, col byte = (d&63) ^ ((row>>1)&3)<<4 (inverse swizzle on source).
  int arowoff[4], browoff[4];
#pragma unroll
  for (int q = 0; q < 4; ++q) {
    const int d = tid * 16 + q * 4096;
    const int row = d >> 6;
    const int col = ((d & 63) ^ (((row >> 1) & 3) << 4)) >> 1;
    arowoff[q] = (mbase + row) * HID_ + col;
    browoff[q] = row * HID_ + col;            // + (prow0+kk)*HID_ at use
  }
  const int wdst = w * 1024;                  // d = w*1024 + lane*16 + q*4096

  auto stage = [&](int u) {
    if (u > 47) u = 47;                       // tail clamp keeps vmcnt accounting uniform
    const int kk = u % 3;
    const int i0 = (u / 3) * 32;
    char* Ab = (char*)smem + (u & 3) * 32768;
    char* Bb = Ab + 16384;
    const u16* ga = wcb + (size_t)kk * (HID_ * HID_) + i0;
    const u16* gb = hin + (size_t)(prow0 + kk) * HID_ + i0;
#pragma unroll
    for (int q = 0; q < 4; ++q) gload16(ga + arowoff[q], Ab + q * 4096 + wdst);
#pragma unroll
    for (int q = 0; q < 4; ++q) gload16(gb + browoff[q], Bb + q * 4096 + wdst);
  };

  f32x16 acc[4][4];
#pragma unroll
  for (int mf = 0; mf < 4; ++mf)
#pragma unroll
    for (int nf = 0; nf < 4; ++nf)
#pragma unroll
      for (int e = 0; e < 16; ++e) acc[mf][nf][e] = 0.f;

  // ds_read bases: logical byte = row*64 + kh*32 + khi*16, row = (wm|wn)*128 + mf|nf*32 + r32;
  // physical = logical ^ ((r32>>1)&3)<<4. Fold kh into two per-lane bases; mf*2048 adds as imm.
  const int swz = ((r32 >> 1) & 3) << 4;
  const int abase = (wm * 128 + r32) * 64 + khi * 16;
  const int bbase = (wn * 128 + r32) * 64 + khi * 16;
  const int aoff0 = abase ^ swz, aoff1 = (abase + 32) ^ swz;
  const int boff0 = bbase ^ swz, boff1 = (bbase + 32) ^ swz;

  bf16x8 a0[2][4], b0[2][4], a1[2][4], b1[2][4];

  // prologue: tiles 0,1,2 staged (24 loads); prove tile 0; read tile 0 into set 0.
  stage(0); stage(1); stage(2);
  asm volatile("s_waitcnt vmcnt(16)" ::: "memory");
  __builtin_amdgcn_sched_barrier(0);
  __builtin_amdgcn_s_barrier();
  __builtin_amdgcn_sched_barrier(0);
  ISSUE_READS(0, a0, b0);

  for (int tt = 0; tt < 24; ++tt) {
    BODY(2 * tt,     a0, b0, a1, b1);
    BODY(2 * tt + 1, a1, b1, a0, b0);
  }

  // epilogue: bias + relu + bf16 store. C/D 32x32 map: col=lane&31,
  // row=(reg&3)+8*(reg>>2)+4*(lane>>5) -> 4 consecutive o per reg-quad.
#pragma unroll
  for (int mf = 0; mf < 4; ++mf)
#pragma unroll
    for (int g = 0; g < 4; ++g) {
      const int o = mbase + wm * 128 + mf * 32 + g * 8 + khi * 4;
      const float4 bias = *(const float4*)&bconv[o];
#pragma unroll
      for (int nf = 0; nf < 4; ++nf) {
        const int n = wn * 128 + nf * 32 + r32;
        const long p = (long)prow0 + 1 + n;
        union { u16 q[4]; uint2 v; } uo;
        uo.q[0] = f2bf(fmaxf(acc[mf][nf][g * 4 + 0] + bias.x, 0.f));
        uo.q[1] = f2bf(fmaxf(acc[mf][nf][g * 4 + 1] + bias.y, 0.f));
        uo.q[2] = f2bf(fmaxf(acc[mf][nf][g * 4 + 2] + bias.z, 0.f));
        uo.q[3] = f2bf(fmaxf(acc[mf][nf][g * 4 + 3] + bias.w, 0.f));
        *(uint2*)&hout[p * HID_ + o] = uo.v;
      }
    }
}

// ---------------- proj_out: out[n][j] = h[n][:] @ W_out[:,j] + b_out (fp32 out) ----------------
__global__ __launch_bounds__(256, 2) void proj_out_gemm(const u16* __restrict__ hin,
                                                        const u16* __restrict__ wob,
                                                        const float* __restrict__ bout,
                                                        float* __restrict__ out) {
  __shared__ __align__(16) u16 Ab[2][128 * 32];   // [n][i]
  __shared__ __align__(16) u16 Bb[2][64 * 32];    // [j][i]
  const int tid = threadIdx.x, wid = tid >> 6, lane = tid & 63;
  const int nt = blockIdx.x;
  const int bb = (nt * 128) / S_, s0v = (nt * 128) % S_;
  const int prow0 = bb * SP_ + s0v + 1;
  const int l4 = lane >> 2, lb = (lane & 3) * 8;
  const int fr = lane & 15, fq = lane >> 4;

  f32x4 acc[2][4];
#pragma unroll
  for (int m = 0; m < 2; ++m)
#pragma unroll
    for (int n = 0; n < 4; ++n) acc[m][n] = {0.f, 0.f, 0.f, 0.f};

  auto stage = [&](int buf, int t) {
    const int i0 = t * 32;
#pragma unroll
    for (int c = 0; c < 2; ++c) {
      const int ch = wid * 2 + c;
      gload16(hin + (long)(prow0 + ch * 16 + l4) * HID_ + i0 + lb, &Ab[buf][ch * 512]);
    }
    gload16(wob + (wid * 16 + l4) * HID_ + i0 + lb, &Bb[buf][wid * 512]);
  };

  stage(0, 0);
  __syncthreads();
  for (int t = 0; t < 16; ++t) {
    const int cur = t & 1;
    if (t < 15) stage(cur ^ 1, t + 1);
    bf16x8 af[2], bfv[4];
#pragma unroll
    for (int m = 0; m < 2; ++m)
      af[m] = *(const bf16x8*)&Ab[cur][(wid * 32 + m * 16 + fr) * 32 + fq * 8];
#pragma unroll
    for (int j = 0; j < 4; ++j)
      bfv[j] = *(const bf16x8*)&Bb[cur][(j * 16 + fr) * 32 + fq * 8];
#pragma unroll
    for (int m = 0; m < 2; ++m)
#pragma unroll
      for (int j = 0; j < 4; ++j)
        acc[m][j] = __builtin_amdgcn_mfma_f32_16x16x32_bf16(af[m], bfv[j], acc[m][j], 0, 0, 0);
    __syncthreads();
  }
  const int n0 = nt * 128;
#pragma unroll
  for (int m = 0; m < 2; ++m) {
    const int nbase = n0 + wid * 32 + m * 16 + fq * 4;
#pragma unroll
    for (int jf = 0; jf < 4; ++jf) {
      const int j = jf * 16 + fr;
      const float bj = bout[j];
#pragma unroll
      for (int r = 0; r < 4; ++r)
        out[(long)(nbase + r) * IN_ + j] = acc[m][jf][r] + bj;
    }
  }
}

extern "C" void kernel_launch(void* const* d_in, const int* in_sizes, int n_in,
                              void* d_out, int out_size, void* d_ws, size_t ws_size,
                              hipStream_t stream) {
  (void)in_sizes; (void)n_in; (void)out_size; (void)ws_size;
  const float* x = (const float*)d_in[0];
  const float* W_in = (const float*)d_in[1];
  const float* b_in = (const float*)d_in[2];
  const float* W_conv = (const float*)d_in[3];
  const float* b_conv = (const float*)d_in[4];
  const float* W_out = (const float*)d_in[5];
  const float* b_out = (const float*)d_in[6];
  float* out = (float*)d_out;
  char* ws = (char*)d_ws;

  const size_t hbytes = (size_t)NP_ * HID_ * sizeof(u16);        // 33,570,816 B
  u16* h0 = (u16*)ws;
  u16* h1 = (u16*)(ws + hbytes);
  u16* wcb = (u16*)(ws + 2 * hbytes);
  u16* wib = (u16*)(ws + 2 * hbytes + (size_t)3 * HID_ * HID_ * 2);
  u16* wob = (u16*)(ws + 2 * hbytes + ((size_t)3 * HID_ * HID_ + IN_ * HID_) * 2);
  u16* xbf = (u16*)(ws + 2 * hbytes + ((size_t)3 * HID_ * HID_ + 2 * IN_ * HID_) * 2);

  // allow 128 KiB dynamic LDS for the conv kernel (host-side attr, idempotent)
  static int lds_attr_set = 0;
  if (!lds_attr_set) {
    (void)hipFuncSetAttribute((const void*)conv_gemm5,
                              hipFuncAttributeMaxDynamicSharedMemorySize, 131072);
    lds_attr_set = 1;
  }

  setup_kernel<<<2048, 256, 0, stream>>>(x, W_conv, W_in, W_out, wcb, wib, wob, xbf, h0, h1);
  proj_in_gemm<<<dim3(NTOT / 128, HID_ / 128), 256, 0, stream>>>(xbf, wib, b_in, h0);
  const u16* cin = h0;
  u16* cout = h1;
  for (int s = 0; s < NSTEP; ++s) {
    conv_gemm5<<<dim3(NTOT / 256, 2), 256, 131072, stream>>>(cin, cout, wcb, b_conv);
    u16* t = (u16*)cin; cin = cout; cout = t;
  }
  proj_out_gemm<<<NTOT / 128, 256, 0, stream>>>(cin, wob, b_out, out);
}

// Round 6
// 759.621 us; speedup vs baseline: 1.0138x; 1.0138x over previous
//
#include <hip/hip_runtime.h>

#define B_ 8
#define S_ 4096
#define IN_ 64
#define HID_ 512
#define NSTEP 12
#define SP_ (S_ + 2)
#define NP_ (B_ * SP_)
#define NTOT (B_ * S_)

typedef unsigned short u16;
typedef __attribute__((ext_vector_type(8))) short bf16x8;
typedef __attribute__((ext_vector_type(4))) float f32x4;
typedef __attribute__((ext_vector_type(16))) float f32x16;

__device__ __forceinline__ u16 f2bf(float f) {
  unsigned u = __float_as_uint(f);
  u += 0x7fffu + ((u >> 16) & 1u);
  return (u16)(u >> 16);
}

__device__ __forceinline__ void gload16(const void* g, void* l) {
  __builtin_amdgcn_global_load_lds((const __attribute__((address_space(1))) void*)g,
                                   (__attribute__((address_space(3))) void*)l, 16, 0, 0);
}

// ---------------- setup: bf16 conversions + weight transposes + pad-row zeroing ----------------
__global__ void setup_kernel(const float* __restrict__ x, const float* __restrict__ Wc,
                             const float* __restrict__ Wi, const float* __restrict__ Wo,
                             u16* __restrict__ wcb, u16* __restrict__ wib,
                             u16* __restrict__ wob, u16* __restrict__ xbf,
                             u16* __restrict__ h0, u16* __restrict__ h1) {
  const int n_wc = 3 * HID_ * HID_;       // wcb[k][o][i] = Wc[o][i][k]
  const int n_wio = IN_ * HID_;
  const int n_xb = NTOT * IN_;
  const int n_pad = 2 * B_ * 2 * HID_;
  const long total = (long)n_wc + 2 * n_wio + n_xb + n_pad;
  for (long u = (long)blockIdx.x * blockDim.x + threadIdx.x; u < total;
       u += (long)gridDim.x * blockDim.x) {
    long v = u;
    if (v < n_wc) {
      int k = (int)(v / (HID_ * HID_));
      int rem = (int)(v % (HID_ * HID_));
      int o = rem / HID_, i = rem % HID_;
      wcb[v] = f2bf(Wc[((long)o * HID_ + i) * 3 + k]);
    } else if ((v -= n_wc) < n_wio) {      // wib[i][j] = Wi[j][i]
      int i = (int)(v / IN_), j = (int)(v % IN_);
      wib[v] = f2bf(Wi[j * HID_ + i]);
    } else if ((v -= n_wio) < n_wio) {     // wob[j][i] = Wo[i][j]
      int j = (int)(v / HID_), i = (int)(v % HID_);
      wob[v] = f2bf(Wo[i * IN_ + j]);
    } else if ((v -= n_wio) < n_xb) {
      xbf[v] = f2bf(x[v]);
    } else {
      v -= n_xb;                           // zero pad rows (s=-1 and s=S per batch, both buffers)
      int buf = (int)(v / (B_ * 2 * HID_));
      int r = (int)(v % (B_ * 2 * HID_));
      int b = r / (2 * HID_);
      int q = r % (2 * HID_);
      int side = q / HID_, i = q % HID_;
      long p = (long)b * SP_ + (side ? (S_ + 1) : 0);
      (buf ? h1 : h0)[p * HID_ + i] = 0;
    }
  }
}

// ---------------- proj_in: h0[n][i] = x[n][:] @ W_in[:,i] + b_in  (bf16 MFMA, K=64) ----------------
__global__ __launch_bounds__(256, 2) void proj_in_gemm(const u16* __restrict__ xb,
                                                       const u16* __restrict__ wib,
                                                       const float* __restrict__ bin,
                                                       u16* __restrict__ hout) {
  __shared__ __align__(16) u16 Ab[128 * 64];
  __shared__ __align__(16) u16 Bb[128 * 64];
  const int tid = threadIdx.x, wid = tid >> 6, lane = tid & 63;
  const int nt = blockIdx.x, mt = blockIdx.y;
  const int wr = wid >> 1, wcn = wid & 1, fr = lane & 15, fq = lane >> 4;
#pragma unroll
  for (int c = 0; c < 4; ++c) {
    const int ch = wid * 4 + c;
    const int row = ch * 8 + (lane >> 3), cb = (lane & 7) * 8;
    gload16(wib + (mt * 128 + row) * 64 + cb, &Ab[ch * 512]);
    gload16(xb + ((long)nt * 128 + row) * 64 + cb, &Bb[ch * 512]);
  }
  f32x4 acc[4][4];
#pragma unroll
  for (int m = 0; m < 4; ++m)
#pragma unroll
    for (int n = 0; n < 4; ++n) acc[m][n] = {0.f, 0.f, 0.f, 0.f};
  __syncthreads();
#pragma unroll
  for (int t = 0; t < 2; ++t) {
    const int j0 = t * 32;
    bf16x8 af[4], bfv[4];
#pragma unroll
    for (int m = 0; m < 4; ++m)
      af[m] = *(const bf16x8*)&Ab[(wr * 64 + m * 16 + fr) * 64 + j0 + fq * 8];
#pragma unroll
    for (int n = 0; n < 4; ++n)
      bfv[n] = *(const bf16x8*)&Bb[(wcn * 64 + n * 16 + fr) * 64 + j0 + fq * 8];
#pragma unroll
    for (int m = 0; m < 4; ++m)
#pragma unroll
      for (int n = 0; n < 4; ++n)
        acc[m][n] = __builtin_amdgcn_mfma_f32_16x16x32_bf16(af[m], bfv[n], acc[m][n], 0, 0, 0);
  }
  const int n0 = nt * 128;
  const int bb = n0 / S_, s0v = n0 % S_;
  const int prow = bb * SP_ + s0v + 1;
#pragma unroll
  for (int m = 0; m < 4; ++m) {
    const int i = mt * 128 + wr * 64 + m * 16 + fq * 4;
    const float4 bias = *(const float4*)&bin[i];
#pragma unroll
    for (int n = 0; n < 4; ++n) {
      const int nl = wcn * 64 + n * 16 + fr;
      const long p = prow + nl;
      union { u16 q[4]; uint2 v; } u;
      u.q[0] = f2bf(acc[m][n][0] + bias.x);
      u.q[1] = f2bf(acc[m][n][1] + bias.y);
      u.q[2] = f2bf(acc[m][n][2] + bias.z);
      u.q[3] = f2bf(acc[m][n][3] + bias.w);
      *(uint2*)&hout[p * HID_ + i] = u.v;
    }
  }
}

// ---------------- conv step: 256x256 tile, 8 waves x (128x64), 32x32x16, frag-major LDS -------
// C[o,n] = relu(sum_{k,i} W[o,i,k] h[i,n+k-1] + b), bf16 in/out.
// K-units u = 0..47: tap kk=u%3, i-slice i0=(u/3)*32 (tap-inner: B re-reads L2-hot).
// LDS: 4 bufs x 32KB, FRAG-MAJOR: buf = [16 A-frags][16 B-frags], each frag = 64
// lanes x 16B = 1KB. A frag fa = mfb*2+kh holds A[mbase+mfb*32+(l&31)][i0+kh*16+(l>>5)*8..+8];
// B frag fb = nfb*2+kh holds h[prow0+kk+nfb*32+(l&31)][same cols]. The per-lane global
// source offset voff=((l&31)*HID+(l>>5)*8) makes gload_lds's implicit dest (+lane*16)
// land each fragment contiguously -> every ds_read_b128 is lane-linear (0 conflicts),
// and LDS staging needs no swizzle at all.
// Body t: vmcnt(8)+barrier -> 6 ds_reads kh0 -> stage(t+3) -> 6 ds_reads kh1 ->
// lgkm(6)+8 MFMA -> lgkm(0)+8 MFMA. Depth-3 prefetch, never vmcnt(0) mid-loop.
__global__ __launch_bounds__(512, 2) void conv_gemm6(const u16* __restrict__ hin,
                                                     u16* __restrict__ hout,
                                                     const u16* __restrict__ wcb,
                                                     const float* __restrict__ bconv) {
  extern __shared__ __align__(16) u16 smem[];
  const int tid = threadIdx.x;
  const int w = tid >> 6, lane = tid & 63;
  const int wm = w >> 2, wn = w & 3;          // 2 x 4 wave grid; per-wave C = 128 x 64
  const int r32 = lane & 31, khi = lane >> 5;
  const int mbase = blockIdx.y * 256;
  const int n0 = blockIdx.x * 256;
  const int bb = n0 / S_, s0 = n0 % S_;
  const int prow0 = bb * SP_ + s0;            // tap-k B rows start at prow0+k

  // per-lane global source offset (elements) shared by every fragment load
  const int voff = r32 * HID_ + khi * 8;

  // wave w stages fragments fid = w*4 .. w*4+3 (fid<16: A, else B)
  auto stage = [&](int u) {
    if (u > 47) u = 47;                       // tail clamp keeps vmcnt accounting uniform
    const int kk = u % 3;
    const int i0 = (u / 3) * 32;
    char* base = (char*)smem + (u & 3) * 32768;
#pragma unroll
    for (int c = 0; c < 4; ++c) {
      const int fid = w * 4 + c;
      const u16* g;
      if (fid < 16) {
        const int mfb = fid >> 1, kh = fid & 1;
        g = wcb + (size_t)kk * (HID_ * HID_) + (size_t)(mbase + mfb * 32) * HID_ + i0 + kh * 16 + voff;
      } else {
        const int fb = fid - 16, nfb = fb >> 1, kh = fb & 1;
        g = hin + (size_t)(prow0 + kk + nfb * 32) * HID_ + i0 + kh * 16 + voff;
      }
      gload16(g, base + fid * 1024);          // dest wave-uniform; HW adds lane*16
    }
  };

  f32x16 acc[4][2];
#pragma unroll
  for (int mf = 0; mf < 4; ++mf)
#pragma unroll
    for (int nf = 0; nf < 2; ++nf)
#pragma unroll
      for (int e = 0; e < 16; ++e) acc[mf][nf][e] = 0.f;

  // ds_read bases (byte): A frag (wm*4+mf)*2+kh -> wm*8192 + (mf*2+kh)*1024 + lane*16
  //                        B frag 16 + (wn*2+nf)*2+kh -> 16384 + wn*4096 + (nf*2+kh)*1024 + lane*16
  const int abase = wm * 8192 + lane * 16;
  const int bbase = 16384 + wn * 4096 + lane * 16;

  // prologue: tiles 0,1,2 staged (12 gloads/wave in flight)
  stage(0); stage(1); stage(2);

#pragma unroll 12
  for (int t = 0; t < 48; ++t) {
    const char* bufp = (const char*)smem + (t & 3) * 32768;

    asm volatile("s_waitcnt vmcnt(8)" ::: "memory");   // tile t fully staged (t+1,t+2 fly)
    __builtin_amdgcn_sched_barrier(0);
    __builtin_amdgcn_s_barrier();
    __builtin_amdgcn_sched_barrier(0);

    bf16x8 af0[4], bf0[2], af1[4], bf1[2];
    // kh0 reads (6)
#pragma unroll
    for (int mf = 0; mf < 4; ++mf)
      af0[mf] = *(const bf16x8*)(bufp + abase + (mf * 2 + 0) * 1024);
#pragma unroll
    for (int nf = 0; nf < 2; ++nf)
      bf0[nf] = *(const bf16x8*)(bufp + bbase + (nf * 2 + 0) * 1024);
    __builtin_amdgcn_sched_barrier(0);
    // prefetch stage for tile t+3 (4 gload_lds)
    stage(t + 3);
    __builtin_amdgcn_sched_barrier(0);
    // kh1 reads (6)
#pragma unroll
    for (int mf = 0; mf < 4; ++mf)
      af1[mf] = *(const bf16x8*)(bufp + abase + (mf * 2 + 1) * 1024);
#pragma unroll
    for (int nf = 0; nf < 2; ++nf)
      bf1[nf] = *(const bf16x8*)(bufp + bbase + (nf * 2 + 1) * 1024);
    __builtin_amdgcn_sched_barrier(0);

    // kh0 MFMA while kh1 reads are serviced
    asm volatile("s_waitcnt lgkmcnt(6)" ::: "memory");
    __builtin_amdgcn_sched_barrier(0);
    __builtin_amdgcn_s_setprio(1);
#pragma unroll
    for (int mf = 0; mf < 4; ++mf)
#pragma unroll
      for (int nf = 0; nf < 2; ++nf)
        acc[mf][nf] = __builtin_amdgcn_mfma_f32_32x32x16_bf16(af0[mf], bf0[nf], acc[mf][nf], 0, 0, 0);
    __builtin_amdgcn_s_setprio(0);
    __builtin_amdgcn_sched_barrier(0);

    asm volatile("s_waitcnt lgkmcnt(0)" ::: "memory");
    __builtin_amdgcn_sched_barrier(0);
    __builtin_amdgcn_s_setprio(1);
#pragma unroll
    for (int mf = 0; mf < 4; ++mf)
#pragma unroll
      for (int nf = 0; nf < 2; ++nf)
        acc[mf][nf] = __builtin_amdgcn_mfma_f32_32x32x16_bf16(af1[mf], bf1[nf], acc[mf][nf], 0, 0, 0);
    __builtin_amdgcn_s_setprio(0);
    __builtin_amdgcn_sched_barrier(0);
  }

  // epilogue: bias + relu + bf16 store. C/D 32x32 map (verified R5): col=lane&31,
  // row=(reg&3)+8*(reg>>2)+4*(lane>>5).
#pragma unroll
  for (int mf = 0; mf < 4; ++mf)
#pragma unroll
    for (int g = 0; g < 4; ++g) {
      const int o = mbase + wm * 128 + mf * 32 + g * 8 + khi * 4;
      const float4 bias = *(const float4*)&bconv[o];
#pragma unroll
      for (int nf = 0; nf < 2; ++nf) {
        const int n = wn * 64 + nf * 32 + r32;
        const long p = (long)prow0 + 1 + n;
        union { u16 q[4]; uint2 v; } uo;
        uo.q[0] = f2bf(fmaxf(acc[mf][nf][g * 4 + 0] + bias.x, 0.f));
        uo.q[1] = f2bf(fmaxf(acc[mf][nf][g * 4 + 1] + bias.y, 0.f));
        uo.q[2] = f2bf(fmaxf(acc[mf][nf][g * 4 + 2] + bias.z, 0.f));
        uo.q[3] = f2bf(fmaxf(acc[mf][nf][g * 4 + 3] + bias.w, 0.f));
        *(uint2*)&hout[p * HID_ + o] = uo.v;
      }
    }
}

// ---------------- proj_out: out[n][j] = h[n][:] @ W_out[:,j] + b_out (fp32 out) ----------------
__global__ __launch_bounds__(256, 2) void proj_out_gemm(const u16* __restrict__ hin,
                                                        const u16* __restrict__ wob,
                                                        const float* __restrict__ bout,
                                                        float* __restrict__ out) {
  __shared__ __align__(16) u16 Ab[2][128 * 32];   // [n][i]
  __shared__ __align__(16) u16 Bb[2][64 * 32];    // [j][i]
  const int tid = threadIdx.x, wid = tid >> 6, lane = tid & 63;
  const int nt = blockIdx.x;
  const int bb = (nt * 128) / S_, s0v = (nt * 128) % S_;
  const int prow0 = bb * SP_ + s0v + 1;
  const int l4 = lane >> 2, lb = (lane & 3) * 8;
  const int fr = lane & 15, fq = lane >> 4;

  f32x4 acc[2][4];
#pragma unroll
  for (int m = 0; m < 2; ++m)
#pragma unroll
    for (int n = 0; n < 4; ++n) acc[m][n] = {0.f, 0.f, 0.f, 0.f};

  auto stage = [&](int buf, int t) {
    const int i0 = t * 32;
#pragma unroll
    for (int c = 0; c < 2; ++c) {
      const int ch = wid * 2 + c;
      gload16(hin + (long)(prow0 + ch * 16 + l4) * HID_ + i0 + lb, &Ab[buf][ch * 512]);
    }
    gload16(wob + (wid * 16 + l4) * HID_ + i0 + lb, &Bb[buf][wid * 512]);
  };

  stage(0, 0);
  __syncthreads();
  for (int t = 0; t < 16; ++t) {
    const int cur = t & 1;
    if (t < 15) stage(cur ^ 1, t + 1);
    bf16x8 af[2], bfv[4];
#pragma unroll
    for (int m = 0; m < 2; ++m)
      af[m] = *(const bf16x8*)&Ab[cur][(wid * 32 + m * 16 + fr) * 32 + fq * 8];
#pragma unroll
    for (int j = 0; j < 4; ++j)
      bfv[j] = *(const bf16x8*)&Bb[cur][(j * 16 + fr) * 32 + fq * 8];
#pragma unroll
    for (int m = 0; m < 2; ++m)
#pragma unroll
      for (int j = 0; j < 4; ++j)
        acc[m][j] = __builtin_amdgcn_mfma_f32_16x16x32_bf16(af[m], bfv[j], acc[m][j], 0, 0, 0);
    __syncthreads();
  }
  const int n0 = nt * 128;
#pragma unroll
  for (int m = 0; m < 2; ++m) {
    const int nbase = n0 + wid * 32 + m * 16 + fq * 4;
#pragma unroll
    for (int jf = 0; jf < 4; ++jf) {
      const int j = jf * 16 + fr;
      const float bj = bout[j];
#pragma unroll
      for (int r = 0; r < 4; ++r)
        out[(long)(nbase + r) * IN_ + j] = acc[m][jf][r] + bj;
    }
  }
}

extern "C" void kernel_launch(void* const* d_in, const int* in_sizes, int n_in,
                              void* d_out, int out_size, void* d_ws, size_t ws_size,
                              hipStream_t stream) {
  (void)in_sizes; (void)n_in; (void)out_size; (void)ws_size;
  const float* x = (const float*)d_in[0];
  const float* W_in = (const float*)d_in[1];
  const float* b_in = (const float*)d_in[2];
  const float* W_conv = (const float*)d_in[3];
  const float* b_conv = (const float*)d_in[4];
  const float* W_out = (const float*)d_in[5];
  const float* b_out = (const float*)d_in[6];
  float* out = (float*)d_out;
  char* ws = (char*)d_ws;

  const size_t hbytes = (size_t)NP_ * HID_ * sizeof(u16);        // 33,570,816 B
  u16* h0 = (u16*)ws;
  u16* h1 = (u16*)(ws + hbytes);
  u16* wcb = (u16*)(ws + 2 * hbytes);
  u16* wib = (u16*)(ws + 2 * hbytes + (size_t)3 * HID_ * HID_ * 2);
  u16* wob = (u16*)(ws + 2 * hbytes + ((size_t)3 * HID_ * HID_ + IN_ * HID_) * 2);
  u16* xbf = (u16*)(ws + 2 * hbytes + ((size_t)3 * HID_ * HID_ + 2 * IN_ * HID_) * 2);

  // allow 128 KiB dynamic LDS for the conv kernel (host-side attr, idempotent)
  static int lds_attr_set = 0;
  if (!lds_attr_set) {
    (void)hipFuncSetAttribute((const void*)conv_gemm6,
                              hipFuncAttributeMaxDynamicSharedMemorySize, 131072);
    lds_attr_set = 1;
  }

  setup_kernel<<<2048, 256, 0, stream>>>(x, W_conv, W_in, W_out, wcb, wib, wob, xbf, h0, h1);
  proj_in_gemm<<<dim3(NTOT / 128, HID_ / 128), 256, 0, stream>>>(xbf, wib, b_in, h0);
  const u16* cin = h0;
  u16* cout = h1;
  for (int s = 0; s < NSTEP; ++s) {
    conv_gemm6<<<dim3(NTOT / 256, 2), 512, 131072, stream>>>(cin, cout, wcb, b_conv);
    u16* t = (u16*)cin; cin = cout; cout = t;
  }
  proj_out_gemm<<<NTOT / 128, 256, 0, stream>>>(cin, wob, b_out, out);
}

// Round 7
// 605.883 us; speedup vs baseline: 1.2710x; 1.2537x over previous
//
#include <hip/hip_runtime.h>

#define B_ 8
#define S_ 4096
#define IN_ 64
#define HID_ 512
#define NSTEP 12
#define SP_ (S_ + 2)
#define NP_ (B_ * SP_)
#define NTOT (B_ * S_)

typedef unsigned short u16;
typedef __attribute__((ext_vector_type(8))) short bf16x8;
typedef __attribute__((ext_vector_type(4))) float f32x4;

__device__ __forceinline__ u16 f2bf(float f) {
  unsigned u = __float_as_uint(f);
  u += 0x7fffu + ((u >> 16) & 1u);
  return (u16)(u >> 16);
}

__device__ __forceinline__ void gload16(const void* g, void* l) {
  __builtin_amdgcn_global_load_lds((const __attribute__((address_space(1))) void*)g,
                                   (__attribute__((address_space(3))) void*)l, 16, 0, 0);
}

// ---------------- setup: bf16 conversions + weight transposes + pad-row zeroing ----------------
__global__ void setup_kernel(const float* __restrict__ x, const float* __restrict__ Wc,
                             const float* __restrict__ Wi, const float* __restrict__ Wo,
                             u16* __restrict__ wcb, u16* __restrict__ wib,
                             u16* __restrict__ wob, u16* __restrict__ xbf,
                             u16* __restrict__ h0, u16* __restrict__ h1) {
  const int n_wc = 3 * HID_ * HID_;       // wcb[k][o][i] = Wc[o][i][k]
  const int n_wio = IN_ * HID_;
  const int n_xb = NTOT * IN_;
  const int n_pad = 2 * B_ * 2 * HID_;
  const long total = (long)n_wc + 2 * n_wio + n_xb + n_pad;
  for (long u = (long)blockIdx.x * blockDim.x + threadIdx.x; u < total;
       u += (long)gridDim.x * blockDim.x) {
    long v = u;
    if (v < n_wc) {
      int k = (int)(v / (HID_ * HID_));
      int rem = (int)(v % (HID_ * HID_));
      int o = rem / HID_, i = rem % HID_;
      wcb[v] = f2bf(Wc[((long)o * HID_ + i) * 3 + k]);
    } else if ((v -= n_wc) < n_wio) {      // wib[i][j] = Wi[j][i]
      int i = (int)(v / IN_), j = (int)(v % IN_);
      wib[v] = f2bf(Wi[j * HID_ + i]);
    } else if ((v -= n_wio) < n_wio) {     // wob[j][i] = Wo[i][j]
      int j = (int)(v / HID_), i = (int)(v % HID_);
      wob[v] = f2bf(Wo[i * IN_ + j]);
    } else if ((v -= n_wio) < n_xb) {
      xbf[v] = f2bf(x[v]);
    } else {
      v -= n_xb;                           // zero pad rows (s=-1 and s=S per batch, both buffers)
      int buf = (int)(v / (B_ * 2 * HID_));
      int r = (int)(v % (B_ * 2 * HID_));
      int b = r / (2 * HID_);
      int q = r % (2 * HID_);
      int side = q / HID_, i = q % HID_;
      long p = (long)b * SP_ + (side ? (S_ + 1) : 0);
      (buf ? h1 : h0)[p * HID_ + i] = 0;
    }
  }
}

// ---------------- proj_in: h0[n][i] = x[n][:] @ W_in[:,i] + b_in  (bf16 MFMA, K=64) ----------------
__global__ __launch_bounds__(256, 2) void proj_in_gemm(const u16* __restrict__ xb,
                                                       const u16* __restrict__ wib,
                                                       const float* __restrict__ bin,
                                                       u16* __restrict__ hout) {
  __shared__ __align__(16) u16 Ab[128 * 64];
  __shared__ __align__(16) u16 Bb[128 * 64];
  const int tid = threadIdx.x, wid = tid >> 6, lane = tid & 63;
  const int nt = blockIdx.x, mt = blockIdx.y;
  const int wr = wid >> 1, wcn = wid & 1, fr = lane & 15, fq = lane >> 4;
#pragma unroll
  for (int c = 0; c < 4; ++c) {
    const int ch = wid * 4 + c;
    const int row = ch * 8 + (lane >> 3), cb = (lane & 7) * 8;
    gload16(wib + (mt * 128 + row) * 64 + cb, &Ab[ch * 512]);
    gload16(xb + ((long)nt * 128 + row) * 64 + cb, &Bb[ch * 512]);
  }
  f32x4 acc[4][4];
#pragma unroll
  for (int m = 0; m < 4; ++m)
#pragma unroll
    for (int n = 0; n < 4; ++n) acc[m][n] = {0.f, 0.f, 0.f, 0.f};
  __syncthreads();
#pragma unroll
  for (int t = 0; t < 2; ++t) {
    const int j0 = t * 32;
    bf16x8 af[4], bfv[4];
#pragma unroll
    for (int m = 0; m < 4; ++m)
      af[m] = *(const bf16x8*)&Ab[(wr * 64 + m * 16 + fr) * 64 + j0 + fq * 8];
#pragma unroll
    for (int n = 0; n < 4; ++n)
      bfv[n] = *(const bf16x8*)&Bb[(wcn * 64 + n * 16 + fr) * 64 + j0 + fq * 8];
#pragma unroll
    for (int m = 0; m < 4; ++m)
#pragma unroll
      for (int n = 0; n < 4; ++n)
        acc[m][n] = __builtin_amdgcn_mfma_f32_16x16x32_bf16(af[m], bfv[n], acc[m][n], 0, 0, 0);
  }
  const int n0 = nt * 128;
  const int bb = n0 / S_, s0v = n0 % S_;
  const int prow = bb * SP_ + s0v + 1;
#pragma unroll
  for (int m = 0; m < 4; ++m) {
    const int i = mt * 128 + wr * 64 + m * 16 + fq * 4;
    const float4 bias = *(const float4*)&bin[i];
#pragma unroll
    for (int n = 0; n < 4; ++n) {
      const int nl = wcn * 64 + n * 16 + fr;
      const long p = prow + nl;
      union { u16 q[4]; uint2 v; } u;
      u.q[0] = f2bf(acc[m][n][0] + bias.x);
      u.q[1] = f2bf(acc[m][n][1] + bias.y);
      u.q[2] = f2bf(acc[m][n][2] + bias.z);
      u.q[3] = f2bf(acc[m][n][3] + bias.w);
      *(uint2*)&hout[p * HID_ + i] = u.v;
    }
  }
}

// ---------------- conv step: R3 geometry + cross-tile register prefetch ----------------
// 256x256 tile, BK=32, 8 waves x (128x64) C, 16x16x32 MFMA, 4 LDS bufs x 32KB,
// depth-3 gload prefetch. NEW vs R3: the 12 ds_read_b128 for tile T+1 are issued
// BEFORE MFMA(T) into the alternate register frag set, so the LDS pipe services
// them under the MFMA burst (they were serialized in R3: 1242+1152 cy -> 2584).
// Sync per BODY(T): vmcnt(4) proves own stage(T+1) retired (entry outstanding = 8:
// tiles T+1,T+2) -> s_barrier publishes stage(T+1) all-waves AND (via program order:
// MFMA(T-1) precedes this barrier, its lgkm wait drained reads(T-1)) makes
// stage(T+3)'s overwrite of buf (T-1)&3 safe -> reads(T+1) -> stage(T+3) -> MFMA(T).
// Never vmcnt(0) in-loop; tail uses clamped dummy stages (vmcnt stays uniform).
#define READS(T, AF, BF) do {                                                  \
    const char* _bp = (const char*)smem + ((T) & 3) * 32768;                   \
    _Pragma("unroll")                                                          \
    for (int _m = 0; _m < 8; ++_m)                                             \
      AF[_m] = *(const bf16x8*)(_bp + aoffs + _m * 1024);                      \
    _Pragma("unroll")                                                          \
    for (int _n = 0; _n < 4; ++_n)                                             \
      BF[_n] = *(const bf16x8*)(_bp + 16384 + boffs + _n * 1024);              \
  } while (0)

#define BODY(T, AFc, BFc, AFn, BFn) do {                                       \
    asm volatile("s_waitcnt vmcnt(4)" ::: "memory");                           \
    __builtin_amdgcn_sched_barrier(0);                                         \
    __builtin_amdgcn_s_barrier();                                              \
    __builtin_amdgcn_sched_barrier(0);                                         \
    READS((T) + 1, AFn, BFn);                                                  \
    __builtin_amdgcn_sched_barrier(0);                                         \
    stage((T) + 3);                                                            \
    __builtin_amdgcn_sched_barrier(0);                                         \
    __builtin_amdgcn_s_setprio(1);                                             \
    _Pragma("unroll")                                                          \
    for (int _m = 0; _m < 8; ++_m)                                             \
      _Pragma("unroll")                                                        \
      for (int _n = 0; _n < 4; ++_n)                                           \
        acc[_m][_n] = __builtin_amdgcn_mfma_f32_16x16x32_bf16(AFc[_m], BFc[_n], acc[_m][_n], 0, 0, 0); \
    __builtin_amdgcn_s_setprio(0);                                             \
    __builtin_amdgcn_sched_barrier(0);                                         \
  } while (0)

__global__ __launch_bounds__(512, 2) void conv_gemm7(const u16* __restrict__ hin,
                                                     u16* __restrict__ hout,
                                                     const u16* __restrict__ wcb,
                                                     const float* __restrict__ bconv) {
  extern __shared__ __align__(16) u16 smem[];
  const int tid = threadIdx.x;
  const int w = tid >> 6, lane = tid & 63;
  const int wm = w >> 2, wn = w & 3;          // 2 x 4 wave grid; per-wave C = 128 x 64
  const int fr = lane & 15, fq = lane >> 4;
  const int mbase = blockIdx.y * 256;
  const int n0 = blockIdx.x * 256;
  const int bb = n0 / S_, s0 = n0 % S_;
  const int prow0 = bb * SP_ + s0;            // tap-k B rows start at prow0+k

  // staging (R3-proven, coalesced 8x128B per instr): linear LDS byte d = tid*16 within
  // an 8KB strip; logical byte = d ^ ((d>>7)&3)<<4 -> pre-swizzled global source.
  const int tl = (tid * 16) ^ (((tid >> 3) & 3) << 4);
  const int srow = tl >> 6;                   // 0..127
  const int scol = (tl & 63) >> 1;            // element col (multiple of 8)
  const int wdst = w * 1024;

  auto stage = [&](int u) {
    if (u > 47) u = 47;                       // tail clamp keeps vmcnt accounting uniform
    const int kk = u % 3;                     // tap-inner: B re-reads L2-hot
    const int i0 = (u / 3) * 32;
    char* base = (char*)smem + (u & 3) * 32768;
    const u16* ga = wcb + (size_t)kk * (HID_ * HID_) + (size_t)(mbase + srow) * HID_ + i0 + scol;
    const u16* gb = hin + (size_t)(prow0 + kk + srow) * HID_ + i0 + scol;
    gload16(ga, base + wdst);
    gload16(ga + 128 * HID_, base + 8192 + wdst);
    gload16(gb, base + 16384 + wdst);
    gload16(gb + 128 * HID_, base + 24576 + wdst);
  };

  f32x4 acc[8][4];
#pragma unroll
  for (int m = 0; m < 8; ++m)
#pragma unroll
    for (int n = 0; n < 4; ++n) acc[m][n] = {0.f, 0.f, 0.f, 0.f};

  // ds_read constants (R3-proven, 0 conflicts): byte = row*64 + fq*16,
  // swizzle XOR = ((fr>>1)&3)<<4 (row>>1 mod 4 depends only on fr).
  const int swzb = ((fr >> 1) & 3) << 4;
  const int aoffs = (((wm * 128 + fr) * 64 + fq * 16)) ^ swzb;
  const int boffs = (((wn * 64 + fr) * 64 + fq * 16)) ^ swzb;

  bf16x8 afA[8], bfA[4], afB[8], bfB[4];

  // prologue: tiles 0,1,2 staged (12 outstanding); prove tile 0; read tile 0 -> set A
  stage(0); stage(1); stage(2);
  asm volatile("s_waitcnt vmcnt(8)" ::: "memory");
  __builtin_amdgcn_sched_barrier(0);
  __builtin_amdgcn_s_barrier();
  __builtin_amdgcn_sched_barrier(0);
  READS(0, afA, bfA);
  __builtin_amdgcn_sched_barrier(0);

#pragma unroll 1
  for (int j = 0; j < 23; ++j) {
    const int T = 2 * j;
    BODY(T,     afA, bfA, afB, bfB);
    BODY(T + 1, afB, bfB, afA, bfA);
  }
  BODY(46, afA, bfA, afB, bfB);

  // final tile 47 (frags in set B; compiler inserts the lgkm drain)
  __builtin_amdgcn_s_setprio(1);
#pragma unroll
  for (int m = 0; m < 8; ++m)
#pragma unroll
    for (int n = 0; n < 4; ++n)
      acc[m][n] = __builtin_amdgcn_mfma_f32_16x16x32_bf16(afB[m], bfB[n], acc[m][n], 0, 0, 0);
  __builtin_amdgcn_s_setprio(0);

  // epilogue: bias + relu + bf16 store (4 consecutive channels per 8B store)
#pragma unroll
  for (int m = 0; m < 8; ++m) {
    const int o = mbase + wm * 128 + m * 16 + fq * 4;
    const float4 bias = *(const float4*)&bconv[o];
#pragma unroll
    for (int n = 0; n < 4; ++n) {
      const int nl = wn * 64 + n * 16 + fr;
      const long p = (long)prow0 + 1 + nl;
      union { u16 q[4]; uint2 v; } u;
      u.q[0] = f2bf(fmaxf(acc[m][n][0] + bias.x, 0.f));
      u.q[1] = f2bf(fmaxf(acc[m][n][1] + bias.y, 0.f));
      u.q[2] = f2bf(fmaxf(acc[m][n][2] + bias.z, 0.f));
      u.q[3] = f2bf(fmaxf(acc[m][n][3] + bias.w, 0.f));
      *(uint2*)&hout[p * HID_ + o] = u.v;
    }
  }
}

// ---------------- proj_out: out[n][j] = h[n][:] @ W_out[:,j] + b_out (fp32 out) ----------------
__global__ __launch_bounds__(256, 2) void proj_out_gemm(const u16* __restrict__ hin,
                                                        const u16* __restrict__ wob,
                                                        const float* __restrict__ bout,
                                                        float* __restrict__ out) {
  __shared__ __align__(16) u16 Ab[2][128 * 32];   // [n][i]
  __shared__ __align__(16) u16 Bb[2][64 * 32];    // [j][i]
  const int tid = threadIdx.x, wid = tid >> 6, lane = tid & 63;
  const int nt = blockIdx.x;
  const int bb = (nt * 128) / S_, s0v = (nt * 128) % S_;
  const int prow0 = bb * SP_ + s0v + 1;
  const int l4 = lane >> 2, lb = (lane & 3) * 8;
  const int fr = lane & 15, fq = lane >> 4;

  f32x4 acc[2][4];
#pragma unroll
  for (int m = 0; m < 2; ++m)
#pragma unroll
    for (int n = 0; n < 4; ++n) acc[m][n] = {0.f, 0.f, 0.f, 0.f};

  auto stage = [&](int buf, int t) {
    const int i0 = t * 32;
#pragma unroll
    for (int c = 0; c < 2; ++c) {
      const int ch = wid * 2 + c;
      gload16(hin + (long)(prow0 + ch * 16 + l4) * HID_ + i0 + lb, &Ab[buf][ch * 512]);
    }
    gload16(wob + (wid * 16 + l4) * HID_ + i0 + lb, &Bb[buf][wid * 512]);
  };

  stage(0, 0);
  __syncthreads();
  for (int t = 0; t < 16; ++t) {
    const int cur = t & 1;
    if (t < 15) stage(cur ^ 1, t + 1);
    bf16x8 af[2], bfv[4];
#pragma unroll
    for (int m = 0; m < 2; ++m)
      af[m] = *(const bf16x8*)&Ab[cur][(wid * 32 + m * 16 + fr) * 32 + fq * 8];
#pragma unroll
    for (int j = 0; j < 4; ++j)
      bfv[j] = *(const bf16x8*)&Bb[cur][(j * 16 + fr) * 32 + fq * 8];
#pragma unroll
    for (int m = 0; m < 2; ++m)
#pragma unroll
      for (int j = 0; j < 4; ++j)
        acc[m][j] = __builtin_amdgcn_mfma_f32_16x16x32_bf16(af[m], bfv[j], acc[m][j], 0, 0, 0);
    __syncthreads();
  }
  const int n0 = nt * 128;
#pragma unroll
  for (int m = 0; m < 2; ++m) {
    const int nbase = n0 + wid * 32 + m * 16 + fq * 4;
#pragma unroll
    for (int jf = 0; jf < 4; ++jf) {
      const int j = jf * 16 + fr;
      const float bj = bout[j];
#pragma unroll
      for (int r = 0; r < 4; ++r)
        out[(long)(nbase + r) * IN_ + j] = acc[m][jf][r] + bj;
    }
  }
}

extern "C" void kernel_launch(void* const* d_in, const int* in_sizes, int n_in,
                              void* d_out, int out_size, void* d_ws, size_t ws_size,
                              hipStream_t stream) {
  (void)in_sizes; (void)n_in; (void)out_size; (void)ws_size;
  const float* x = (const float*)d_in[0];
  const float* W_in = (const float*)d_in[1];
  const float* b_in = (const float*)d_in[2];
  const float* W_conv = (const float*)d_in[3];
  const float* b_conv = (const float*)d_in[4];
  const float* W_out = (const float*)d_in[5];
  const float* b_out = (const float*)d_in[6];
  float* out = (float*)d_out;
  char* ws = (char*)d_ws;

  const size_t hbytes = (size_t)NP_ * HID_ * sizeof(u16);        // 33,570,816 B
  u16* h0 = (u16*)ws;
  u16* h1 = (u16*)(ws + hbytes);
  u16* wcb = (u16*)(ws + 2 * hbytes);
  u16* wib = (u16*)(ws + 2 * hbytes + (size_t)3 * HID_ * HID_ * 2);
  u16* wob = (u16*)(ws + 2 * hbytes + ((size_t)3 * HID_ * HID_ + IN_ * HID_) * 2);
  u16* xbf = (u16*)(ws + 2 * hbytes + ((size_t)3 * HID_ * HID_ + 2 * IN_ * HID_) * 2);

  // allow 128 KiB dynamic LDS for the conv kernel (host-side attr, idempotent)
  static int lds_attr_set = 0;
  if (!lds_attr_set) {
    (void)hipFuncSetAttribute((const void*)conv_gemm7,
                              hipFuncAttributeMaxDynamicSharedMemorySize, 131072);
    lds_attr_set = 1;
  }

  setup_kernel<<<2048, 256, 0, stream>>>(x, W_conv, W_in, W_out, wcb, wib, wob, xbf, h0, h1);
  proj_in_gemm<<<dim3(NTOT / 128, HID_ / 128), 256, 0, stream>>>(xbf, wib, b_in, h0);
  const u16* cin = h0;
  u16* cout = h1;
  for (int s = 0; s < NSTEP; ++s) {
    conv_gemm7<<<dim3(NTOT / 256, 2), 512, 131072, stream>>>(cin, cout, wcb, b_conv);
    u16* t = (u16*)cin; cin = cout; cout = t;
  }
  proj_out_gemm<<<NTOT / 128, 256, 0, stream>>>(cin, wob, b_out, out);
}

// Round 8
// 597.986 us; speedup vs baseline: 1.2878x; 1.0132x over previous
//
#include <hip/hip_runtime.h>

#define B_ 8
#define S_ 4096
#define IN_ 64
#define HID_ 512
#define NSTEP 12
#define SP_ (S_ + 2)
#define NP_ (B_ * SP_)
#define NTOT (B_ * S_)

typedef unsigned short u16;
typedef __attribute__((ext_vector_type(8))) short bf16x8;
typedef __attribute__((ext_vector_type(4))) float f32x4;

__device__ __forceinline__ u16 f2bf(float f) {
  unsigned u = __float_as_uint(f);
  u += 0x7fffu + ((u >> 16) & 1u);
  return (u16)(u >> 16);
}

__device__ __forceinline__ void gload16(const void* g, void* l) {
  __builtin_amdgcn_global_load_lds((const __attribute__((address_space(1))) void*)g,
                                   (__attribute__((address_space(3))) void*)l, 16, 0, 0);
}

// ---------------- setup: bf16 conversions + weight transposes + pad-row zeroing ----------------
__global__ void setup_kernel(const float* __restrict__ x, const float* __restrict__ Wc,
                             const float* __restrict__ Wi, const float* __restrict__ Wo,
                             u16* __restrict__ wcb, u16* __restrict__ wib,
                             u16* __restrict__ wob, u16* __restrict__ xbf,
                             u16* __restrict__ h0, u16* __restrict__ h1) {
  const int n_wc = 3 * HID_ * HID_;       // wcb[k][o][i] = Wc[o][i][k]
  const int n_wio = IN_ * HID_;
  const int n_xb = NTOT * IN_;
  const int n_pad = 2 * B_ * 2 * HID_;
  const long total = (long)n_wc + 2 * n_wio + n_xb + n_pad;
  for (long u = (long)blockIdx.x * blockDim.x + threadIdx.x; u < total;
       u += (long)gridDim.x * blockDim.x) {
    long v = u;
    if (v < n_wc) {
      int k = (int)(v / (HID_ * HID_));
      int rem = (int)(v % (HID_ * HID_));
      int o = rem / HID_, i = rem % HID_;
      wcb[v] = f2bf(Wc[((long)o * HID_ + i) * 3 + k]);
    } else if ((v -= n_wc) < n_wio) {      // wib[i][j] = Wi[j][i]
      int i = (int)(v / IN_), j = (int)(v % IN_);
      wib[v] = f2bf(Wi[j * HID_ + i]);
    } else if ((v -= n_wio) < n_wio) {     // wob[j][i] = Wo[i][j]
      int j = (int)(v / HID_), i = (int)(v % HID_);
      wob[v] = f2bf(Wo[i * IN_ + j]);
    } else if ((v -= n_wio) < n_xb) {
      xbf[v] = f2bf(x[v]);
    } else {
      v -= n_xb;                           // zero pad rows (s=-1 and s=S per batch, both buffers)
      int buf = (int)(v / (B_ * 2 * HID_));
      int r = (int)(v % (B_ * 2 * HID_));
      int b = r / (2 * HID_);
      int q = r % (2 * HID_);
      int side = q / HID_, i = q % HID_;
      long p = (long)b * SP_ + (side ? (S_ + 1) : 0);
      (buf ? h1 : h0)[p * HID_ + i] = 0;
    }
  }
}

// ---------------- proj_in: h0[n][i] = x[n][:] @ W_in[:,i] + b_in  (bf16 MFMA, K=64) ----------------
__global__ __launch_bounds__(256, 2) void proj_in_gemm(const u16* __restrict__ xb,
                                                       const u16* __restrict__ wib,
                                                       const float* __restrict__ bin,
                                                       u16* __restrict__ hout) {
  __shared__ __align__(16) u16 Ab[128 * 64];
  __shared__ __align__(16) u16 Bb[128 * 64];
  const int tid = threadIdx.x, wid = tid >> 6, lane = tid & 63;
  const int nt = blockIdx.x, mt = blockIdx.y;
  const int wr = wid >> 1, wcn = wid & 1, fr = lane & 15, fq = lane >> 4;
#pragma unroll
  for (int c = 0; c < 4; ++c) {
    const int ch = wid * 4 + c;
    const int row = ch * 8 + (lane >> 3), cb = (lane & 7) * 8;
    gload16(wib + (mt * 128 + row) * 64 + cb, &Ab[ch * 512]);
    gload16(xb + ((long)nt * 128 + row) * 64 + cb, &Bb[ch * 512]);
  }
  f32x4 acc[4][4];
#pragma unroll
  for (int m = 0; m < 4; ++m)
#pragma unroll
    for (int n = 0; n < 4; ++n) acc[m][n] = {0.f, 0.f, 0.f, 0.f};
  __syncthreads();
#pragma unroll
  for (int t = 0; t < 2; ++t) {
    const int j0 = t * 32;
    bf16x8 af[4], bfv[4];
#pragma unroll
    for (int m = 0; m < 4; ++m)
      af[m] = *(const bf16x8*)&Ab[(wr * 64 + m * 16 + fr) * 64 + j0 + fq * 8];
#pragma unroll
    for (int n = 0; n < 4; ++n)
      bfv[n] = *(const bf16x8*)&Bb[(wcn * 64 + n * 16 + fr) * 64 + j0 + fq * 8];
#pragma unroll
    for (int m = 0; m < 4; ++m)
#pragma unroll
      for (int n = 0; n < 4; ++n)
        acc[m][n] = __builtin_amdgcn_mfma_f32_16x16x32_bf16(af[m], bfv[n], acc[m][n], 0, 0, 0);
  }
  const int n0 = nt * 128;
  const int bb = n0 / S_, s0v = n0 % S_;
  const int prow = bb * SP_ + s0v + 1;
#pragma unroll
  for (int m = 0; m < 4; ++m) {
    const int i = mt * 128 + wr * 64 + m * 16 + fq * 4;
    const float4 bias = *(const float4*)&bin[i];
#pragma unroll
    for (int n = 0; n < 4; ++n) {
      const int nl = wcn * 64 + n * 16 + fr;
      const long p = prow + nl;
      union { u16 q[4]; uint2 v; } u;
      u.q[0] = f2bf(acc[m][n][0] + bias.x);
      u.q[1] = f2bf(acc[m][n][1] + bias.y);
      u.q[2] = f2bf(acc[m][n][2] + bias.z);
      u.q[3] = f2bf(acc[m][n][3] + bias.w);
      *(uint2*)&hout[p * HID_ + i] = u.v;
    }
  }
}

// ---------------- conv step: 256x256, BK=64, 2 dbuf, m201-ordered 8-phase ----------------
// C[o,n] = relu(sum_{k,i} W[o,i,k] h[i,n+k-1] + b), bf16 in/out.
// K-units u = 0..23: tap kk=u%3, i-slice i0=(u/3)*64 (tap-inner: B re-reads L2-hot).
// LDS: A d0 [0,32K) A d1 [32K,64K) B d0 [64K,96K) B d1 [96K,128K); each half = 256
// rows x 128 B, strips of 64 rows; swizzle byte ^= ((row&7)<<4) both sides (R4-verified).
// PHASE ORDER (m201): {ds_reads; stage; BARRIER; lgkm(0); setprio+16 MFMA; [vmcnt(4)];
// BARRIER} — reads issued BEFORE the barrier so the LDS pipe services them under the
// barrier wait / co-wave MFMA backpressure; lgkm(0) after the barrier (rule #18:
// sched_barrier(0) follows it). Gates vmcnt(4) close phases 1/4/5/8:
//   ph1-end: outstanding [SA1d0,SA0d1,SB0d1'] -> drains SA1d0 (ph2 reads it)
//   ph4-end: [SA0d1,SB0d1',SB1d1',SA1d1',SA0d0'] -> drains SA0/SB0/SB1 d1 (ph5)
//   ph5-end: [SA1d1',SA0d0',SB0d0'] -> drains SA1d1' (ph6)
//   ph8-end: [SA0d0',SB0d0',SB1d0',SA1d0',SA0d1''] -> drains SA0/SB0/SB1 d0 (ph1')
// WAR: each restage slot is >=1 closing-barrier after its region's last reader's lgkm0.
// Never vmcnt(0) mid-loop; tail clamps stage source u (dest fixed per slot).
#define LDA(D, MH, KH) do {                                                     \
    const char* _p = (const char*)smem + (D) * 32768 + (wm * 2 + (MH)) * 8192   \
                     + arow + ((KH) ? ck1 : ck0);                               \
    af[0] = *(const bf16x8*)(_p);                                               \
    af[1] = *(const bf16x8*)(_p + 2048);                                        \
    af[2] = *(const bf16x8*)(_p + 4096);                                        \
    af[3] = *(const bf16x8*)(_p + 6144);                                        \
  } while (0)

#define LDB(D, KH) do {                                                         \
    const char* _p = (const char*)smem + 65536 + (D) * 32768 + wn * 8192        \
                     + arow + ((KH) ? ck1 : ck0);                               \
    bf[0] = *(const bf16x8*)(_p);                                               \
    bf[1] = *(const bf16x8*)(_p + 2048);                                        \
    bf[2] = *(const bf16x8*)(_p + 4096);                                        \
    bf[3] = *(const bf16x8*)(_p + 6144);                                        \
  } while (0)

#define MFMA16(MB)                                                              \
  _Pragma("unroll")                                                             \
  for (int mf = 0; mf < 4; ++mf)                                                \
    _Pragma("unroll")                                                           \
    for (int nf = 0; nf < 4; ++nf)                                              \
      acc[(MB) + mf][nf] = __builtin_amdgcn_mfma_f32_16x16x32_bf16(af[mf], bf[nf], acc[(MB) + mf][nf], 0, 0, 0)

#define PHASE_TAIL(GATE, MB) do {                                               \
    __builtin_amdgcn_sched_barrier(0);                                          \
    __builtin_amdgcn_s_barrier();                                               \
    asm volatile("s_waitcnt lgkmcnt(0)" ::: "memory");                          \
    __builtin_amdgcn_sched_barrier(0);                                          \
    __builtin_amdgcn_s_setprio(1);                                              \
    MFMA16(MB);                                                                 \
    __builtin_amdgcn_s_setprio(0);                                              \
    __builtin_amdgcn_sched_barrier(0);                                          \
    if (GATE) { asm volatile("s_waitcnt vmcnt(4)" ::: "memory"); }              \
    __builtin_amdgcn_sched_barrier(0);                                          \
    __builtin_amdgcn_s_barrier();                                               \
    __builtin_amdgcn_sched_barrier(0);                                          \
  } while (0)

__global__ __launch_bounds__(512, 2) void conv_gemm8(const u16* __restrict__ hin,
                                                     u16* __restrict__ hout,
                                                     const u16* __restrict__ wcb,
                                                     const float* __restrict__ bconv) {
  extern __shared__ __align__(16) u16 smem[];
  const int tid = threadIdx.x;
  const int w = tid >> 6, lane = tid & 63;
  const int wm = w >> 2, wn = w & 3;          // 2 x 4 wave grid; per-wave C = 128 x 64
  const int fr = lane & 15, fq = lane >> 4;
  const int mbase = blockIdx.y * 256;
  const int n0 = blockIdx.x * 256;
  const int bb = n0 / S_, s0 = n0 % S_;
  const int prow0 = bb * SP_ + s0;            // tap-k B rows start at prow0+k

  // staging per-thread coords (R4-verified): linear byte in an 8KB strip = tid*16;
  // logical row = tid>>3, col = (tid&7)*16 ^ ((row&7)<<4) (inverse swizzle on source).
  const int srow = tid >> 3;                  // 0..63
  const int scol = (((tid & 7) * 16) ^ (((tid >> 3) & 7) << 4)) >> 1;
  const int wdst = w * 1024;

  // stage one region (2 x gload16 = 16KB) of K-tile u into dbuf d. r: 0=SA0,1=SB0,2=SB1,3=SA1
  auto stage = [&](int d, int u, int r) {
    if (u > 23) u = 23;                       // tail clamp (dest stays slot-correct)
    const int kk = u % 3;
    const int i0 = (u / 3) * 64;
    if (r == 0 || r == 3) {
      const int rb = (r == 0) ? 0 : 64;
      char* dst = (char*)smem + d * 32768 + rb * 128;
      const u16* g = wcb + (size_t)kk * (HID_ * HID_) + (size_t)(mbase + rb + srow) * HID_ + i0 + scol;
      gload16(g, dst + wdst);
      gload16(g + 128 * HID_, dst + 16384 + wdst);
    } else {
      const int rb = (r == 1) ? 0 : 128;
      char* dst = (char*)smem + 65536 + d * 32768 + rb * 128;
      const u16* g = hin + (size_t)(prow0 + kk + rb + srow) * HID_ + i0 + scol;
      gload16(g, dst + wdst);
      gload16(g + 64 * HID_, dst + 8192 + wdst);
    }
  };

  f32x4 acc[8][4];
#pragma unroll
  for (int m = 0; m < 8; ++m)
#pragma unroll
    for (int n = 0; n < 4; ++n) acc[m][n] = {0.f, 0.f, 0.f, 0.f};

  // ds_read constants: row byte = (m*16+fr)*128 within strip; col = kh*64 + fq*16,
  // XOR-swizzled by ((fr&7)<<4). XOR computed per-kh (bit6 overlaps).
  const int swz = (fr & 7) << 4;
  const int ck0 = (fq * 16) ^ swz;
  const int ck1 = (64 + fq * 16) ^ swz;
  const int arow = fr * 128;

  // prologue: slots ph4..ph8 of virtual iter -1: tile0 (d0) all regions + tile1 SA0(d1)
  stage(0, 0, 0); stage(0, 0, 1); stage(0, 0, 2); stage(0, 0, 3);
  stage(1, 1, 0);
  asm volatile("s_waitcnt vmcnt(4)" ::: "memory");   // proves SA0/SB0/SB1 d0
  __builtin_amdgcn_sched_barrier(0);
  __builtin_amdgcn_s_barrier();
  __builtin_amdgcn_sched_barrier(0);

  bf16x8 af[4], bf[4];

#pragma unroll 1
  for (int j = 0; j < 12; ++j) {
    const int u1 = 2 * j + 1, u2 = 2 * j + 2, u3 = 2 * j + 3;

    LDA(0, 0, 0); LDB(0, 0); stage(1, u1, 1);   // ph1
    PHASE_TAIL(1, 0);
    LDA(0, 1, 0);            stage(1, u1, 2);   // ph2 (bf from ph1)
    PHASE_TAIL(0, 4);
    LDA(0, 0, 1); LDB(0, 1); stage(1, u1, 3);   // ph3
    PHASE_TAIL(0, 0);
    LDA(0, 1, 1);            stage(0, u2, 0);   // ph4
    PHASE_TAIL(1, 4);
    LDA(1, 0, 0); LDB(1, 0); stage(0, u2, 1);   // ph5
    PHASE_TAIL(1, 0);
    LDA(1, 1, 0);            stage(0, u2, 2);   // ph6
    PHASE_TAIL(0, 4);
    LDA(1, 0, 1); LDB(1, 1); stage(0, u2, 3);   // ph7
    PHASE_TAIL(0, 0);
    LDA(1, 1, 1);            stage(1, u3, 0);   // ph8
    PHASE_TAIL(1, 4);
  }

  // epilogue: bias + relu + bf16 store (4 consecutive channels per 8B store)
#pragma unroll
  for (int m = 0; m < 8; ++m) {
    const int o = mbase + wm * 128 + m * 16 + fq * 4;
    const float4 bias = *(const float4*)&bconv[o];
#pragma unroll
    for (int n = 0; n < 4; ++n) {
      const int nl = wn * 64 + n * 16 + fr;
      const long p = (long)prow0 + 1 + nl;
      union { u16 q[4]; uint2 v; } u;
      u.q[0] = f2bf(fmaxf(acc[m][n][0] + bias.x, 0.f));
      u.q[1] = f2bf(fmaxf(acc[m][n][1] + bias.y, 0.f));
      u.q[2] = f2bf(fmaxf(acc[m][n][2] + bias.z, 0.f));
      u.q[3] = f2bf(fmaxf(acc[m][n][3] + bias.w, 0.f));
      *(uint2*)&hout[p * HID_ + o] = u.v;
    }
  }
}

// ---------------- proj_out: out[n][j] = h[n][:] @ W_out[:,j] + b_out (fp32 out) ----------------
__global__ __launch_bounds__(256, 2) void proj_out_gemm(const u16* __restrict__ hin,
                                                        const u16* __restrict__ wob,
                                                        const float* __restrict__ bout,
                                                        float* __restrict__ out) {
  __shared__ __align__(16) u16 Ab[2][128 * 32];   // [n][i]
  __shared__ __align__(16) u16 Bb[2][64 * 32];    // [j][i]
  const int tid = threadIdx.x, wid = tid >> 6, lane = tid & 63;
  const int nt = blockIdx.x;
  const int bb = (nt * 128) / S_, s0v = (nt * 128) % S_;
  const int prow0 = bb * SP_ + s0v + 1;
  const int l4 = lane >> 2, lb = (lane & 3) * 8;
  const int fr = lane & 15, fq = lane >> 4;

  f32x4 acc[2][4];
#pragma unroll
  for (int m = 0; m < 2; ++m)
#pragma unroll
    for (int n = 0; n < 4; ++n) acc[m][n] = {0.f, 0.f, 0.f, 0.f};

  auto stage = [&](int buf, int t) {
    const int i0 = t * 32;
#pragma unroll
    for (int c = 0; c < 2; ++c) {
      const int ch = wid * 2 + c;
      gload16(hin + (long)(prow0 + ch * 16 + l4) * HID_ + i0 + lb, &Ab[buf][ch * 512]);
    }
    gload16(wob + (wid * 16 + l4) * HID_ + i0 + lb, &Bb[buf][wid * 512]);
  };

  stage(0, 0);
  __syncthreads();
  for (int t = 0; t < 16; ++t) {
    const int cur = t & 1;
    if (t < 15) stage(cur ^ 1, t + 1);
    bf16x8 af[2], bfv[4];
#pragma unroll
    for (int m = 0; m < 2; ++m)
      af[m] = *(const bf16x8*)&Ab[cur][(wid * 32 + m * 16 + fr) * 32 + fq * 8];
#pragma unroll
    for (int j = 0; j < 4; ++j)
      bfv[j] = *(const bf16x8*)&Bb[cur][(j * 16 + fr) * 32 + fq * 8];
#pragma unroll
    for (int m = 0; m < 2; ++m)
#pragma unroll
      for (int j = 0; j < 4; ++j)
        acc[m][j] = __builtin_amdgcn_mfma_f32_16x16x32_bf16(af[m], bfv[j], acc[m][j], 0, 0, 0);
    __syncthreads();
  }
  const int n0 = nt * 128;
#pragma unroll
  for (int m = 0; m < 2; ++m) {
    const int nbase = n0 + wid * 32 + m * 16 + fq * 4;
#pragma unroll
    for (int jf = 0; jf < 4; ++jf) {
      const int j = jf * 16 + fr;
      const float bj = bout[j];
#pragma unroll
      for (int r = 0; r < 4; ++r)
        out[(long)(nbase + r) * IN_ + j] = acc[m][jf][r] + bj;
    }
  }
}

extern "C" void kernel_launch(void* const* d_in, const int* in_sizes, int n_in,
                              void* d_out, int out_size, void* d_ws, size_t ws_size,
                              hipStream_t stream) {
  (void)in_sizes; (void)n_in; (void)out_size; (void)ws_size;
  const float* x = (const float*)d_in[0];
  const float* W_in = (const float*)d_in[1];
  const float* b_in = (const float*)d_in[2];
  const float* W_conv = (const float*)d_in[3];
  const float* b_conv = (const float*)d_in[4];
  const float* W_out = (const float*)d_in[5];
  const float* b_out = (const float*)d_in[6];
  float* out = (float*)d_out;
  char* ws = (char*)d_ws;

  const size_t hbytes = (size_t)NP_ * HID_ * sizeof(u16);        // 33,570,816 B
  u16* h0 = (u16*)ws;
  u16* h1 = (u16*)(ws + hbytes);
  u16* wcb = (u16*)(ws + 2 * hbytes);
  u16* wib = (u16*)(ws + 2 * hbytes + (size_t)3 * HID_ * HID_ * 2);
  u16* wob = (u16*)(ws + 2 * hbytes + ((size_t)3 * HID_ * HID_ + IN_ * HID_) * 2);
  u16* xbf = (u16*)(ws + 2 * hbytes + ((size_t)3 * HID_ * HID_ + 2 * IN_ * HID_) * 2);

  // allow 128 KiB dynamic LDS for the conv kernel (host-side attr, idempotent)
  static int lds_attr_set = 0;
  if (!lds_attr_set) {
    (void)hipFuncSetAttribute((const void*)conv_gemm8,
                              hipFuncAttributeMaxDynamicSharedMemorySize, 131072);
    lds_attr_set = 1;
  }

  setup_kernel<<<2048, 256, 0, stream>>>(x, W_conv, W_in, W_out, wcb, wib, wob, xbf, h0, h1);
  proj_in_gemm<<<dim3(NTOT / 128, HID_ / 128), 256, 0, stream>>>(xbf, wib, b_in, h0);
  const u16* cin = h0;
  u16* cout = h1;
  for (int s = 0; s < NSTEP; ++s) {
    conv_gemm8<<<dim3(NTOT / 256, 2), 512, 131072, stream>>>(cin, cout, wcb, b_conv);
    u16* t = (u16*)cin; cin = cout; cout = t;
  }
  proj_out_gemm<<<NTOT / 128, 256, 0, stream>>>(cin, wob, b_out, out);
}